// Round 1
// 281.693 us; speedup vs baseline: 1.0145x; 1.0145x over previous
//
#include <hip/hip_runtime.h>
#include <hip/hip_bf16.h>
#include <hip/hip_fp8.h>

typedef __bf16 bf16x8 __attribute__((ext_vector_type(8)));
typedef float floatx4 __attribute__((ext_vector_type(4)));

// ---- Cl(3) Cayley table, row i = first operand, col j = second. p = i*8+j ----
constexpr int TK[64] = {
  0,1,2,3,4,5,6,7,
  1,0,4,5,2,3,7,6,
  2,4,0,6,1,7,3,5,
  3,5,6,0,7,1,2,4,
  4,2,1,7,0,6,5,3,
  5,3,7,1,6,0,4,2,
  6,7,3,2,5,4,0,1,
  7,6,5,4,3,2,1,0
};
constexpr float SGN[64] = {
  1, 1, 1, 1, 1, 1, 1, 1,
  1, 1, 1, 1, 1, 1, 1, 1,
  1,-1, 1, 1,-1,-1, 1,-1,
  1,-1,-1, 1, 1,-1,-1, 1,
  1,-1, 1, 1,-1,-1, 1,-1,
  1,-1,-1, 1, 1,-1,-1, 1,
  1, 1,-1, 1,-1, 1,-1,-1,
  1, 1,-1, 1,-1, 1,-1,-1
};

__device__ __forceinline__ void async16(const void* g, void* l) {
  __builtin_amdgcn_global_load_lds(
      (const __attribute__((address_space(1))) void*)g,
      (__attribute__((address_space(3))) void*)l, 16, 0, 0);
}

__device__ __forceinline__ unsigned char to_fp8(float v) {
  __hip_fp8_e4m3 q(v);
  return (unsigned char)q.__x;
}

// ---- transpose+cast fp32 [K=256][N=1024] -> bf16 B_il[n][256] with g/u 32-interleave ----
// dst row n = (f>>5)*64 + sel*32 + (f&31)
__global__ __launch_bounds__(256) void transpose_cast_gu(
    const float* __restrict__ src, __bf16* __restrict__ dst, int sel)
{
  __shared__ float s[32 * 33];
  const int t = threadIdx.x;
  const int k0 = blockIdx.y * 32, f0 = blockIdx.x * 32;
  const int r = t >> 5, c = t & 31;
  #pragma unroll
  for (int i = 0; i < 4; ++i)
    s[(r + i * 8) * 33 + c] = src[(size_t)(k0 + r + i * 8) * 1024 + f0 + c];
  __syncthreads();
  #pragma unroll
  for (int i = 0; i < 4; ++i) {
    int f = f0 + r + i * 8;
    int n = ((f >> 5) << 6) + sel * 32 + (f & 31);
    dst[(size_t)n * 256 + k0 + c] = (__bf16)s[c * 33 + r + i * 8];
  }
}

// ---- transpose+cast fp32 [K][N] -> fp8 [N][K], value*16 ----
__global__ __launch_bounds__(256) void transpose_cast_fp8(
    const float* __restrict__ src, unsigned char* __restrict__ dst, int K, int N)
{
  __shared__ float s[32 * 33];
  const int t = threadIdx.x;
  const int k0 = blockIdx.y * 32, n0 = blockIdx.x * 32;
  const int r = t >> 5, c = t & 31;
  #pragma unroll
  for (int i = 0; i < 4; ++i)
    s[(r + i * 8) * 33 + c] = src[(size_t)(k0 + r + i * 8) * N + n0 + c];
  __syncthreads();
  #pragma unroll
  for (int i = 0; i < 4; ++i)
    dst[(size_t)(n0 + r + i * 8) * K + k0 + c] = to_fp8(16.f * s[c * 33 + r + i * 8]);
}

// ---- geometric product + gate mix + LayerNorm -> bf16 flat [65536][256] ----
__global__ __launch_bounds__(256) void geo_ln(
    const float* __restrict__ X,   // [8192][8][256]
    const float* __restrict__ IW,  // [64]
    const float* __restrict__ GG,  // [1]
    const float* __restrict__ LW, const float* __restrict__ LB,
    __bf16* __restrict__ F)        // [65536][256]
{
  __shared__ float sw[64];
  __shared__ float smix[8 * 256];
  __shared__ float sstat[16];
  const int t = threadIdx.x;
  const int tok = blockIdx.x;

  if (t < 64) sw[t] = SGN[t] / (1.f + __expf(-IW[t]));

  float xv[8];
  #pragma unroll
  for (int b = 0; b < 8; ++b) xv[b] = X[(size_t)tok * 2048 + b * 256 + t];
  const float g = 1.f / (1.f + __expf(-GG[0]));

  __syncthreads();

  float geo[8] = {0.f, 0.f, 0.f, 0.f, 0.f, 0.f, 0.f, 0.f};
  #pragma unroll
  for (int p = 0; p < 64; ++p)
    geo[TK[p]] += xv[p >> 3] * xv[p & 7] * sw[p];

  float mv[8];
  #pragma unroll
  for (int b = 0; b < 8; ++b) {
    mv[b] = g * geo[b] + (1.f - g) * xv[b];
    smix[b * 256 + t] = mv[b];
  }
  __syncthreads();

  const int wv = t >> 6, lane = t & 63;
  #pragma unroll
  for (int s = 0; s < 2; ++s) {
    int b = wv * 2 + s;
    float v0 = smix[b * 256 + lane];
    float v1 = smix[b * 256 + 64 + lane];
    float v2 = smix[b * 256 + 128 + lane];
    float v3 = smix[b * 256 + 192 + lane];
    float sum = v0 + v1 + v2 + v3;
    float sq  = v0*v0 + v1*v1 + v2*v2 + v3*v3;
    #pragma unroll
    for (int off = 32; off > 0; off >>= 1) {
      sum += __shfl_xor(sum, off, 64);
      sq  += __shfl_xor(sq,  off, 64);
    }
    if (lane == 0) {
      float mu  = sum * (1.f / 256.f);
      float var = sq * (1.f / 256.f) - mu * mu;
      sstat[b]     = mu;
      sstat[8 + b] = rsqrtf(var + 1e-5f);
    }
  }
  __syncthreads();

  const float lw = LW[t], lb = LB[t];
  #pragma unroll
  for (int b = 0; b < 8; ++b) {
    float v = (mv[b] - sstat[b]) * sstat[8 + b] * lw + lb;
    F[(size_t)(tok * 8 + b) * 256 + t] = (__bf16)v;
  }
}

// ---- Kernel C: gate+up GEMM + SwiGLU -> h fp8 (x16) ----
// 256m x 256n (n = g/u 32-interleaved, so per-wave nj/nj+2 pair = same f cols),
// BK=64, 8 waves (2Mx4N), per-wave 128x64, 16x16x32 bf16 MFMA.
// Single 64KB LDS buffer recycled at quarter-tile granularity; 4 phases/K-tile,
// counted vmcnt (never 0 in steady state); T2 XOR-swizzle; T5 setprio; T1 XCD swizzle.
__global__ __launch_bounds__(512, 2) void gemm_gateup(
    const __bf16* __restrict__ A,   // flat [65536][256]
    const __bf16* __restrict__ B,   // B_il [2048][256]
    unsigned char* __restrict__ H)  // fp8 [65536][1024]
{
  __shared__ __align__(16) char smc[65536];   // [0,32K) = A tile, [32K,64K) = B tile

  const int t = threadIdx.x;
  const int l = t & 63;
  const int wv = t >> 6, wm = wv & 1, wn = wv >> 1;
  const int j4 = l >> 4;

  // XCD-aware bijective swizzle: all 8 n-blocks of an m-panel on one XCD
  const int bid = blockIdx.x;
  const int lid = (bid & 7) * 256 + (bid >> 3);
  const int m0 = (lid >> 3) * 256;
  const int n0 = (lid & 7) * 256;

  // ---- staging source/dest (pre-swizzled source, linear LDS dest) ----
  const int rA = t >> 3;                               // 0..63
  const int rB = ((t >> 8) * 64) + ((t & 255) >> 3);   // 0..31, 64..95
  const int cs = ((t & 7) ^ ((t >> 3) & 7)) * 8;       // swizzled k-slot, elements
  const __bf16* gA = A + (size_t)(m0 + rA) * 256 + cs;
  const __bf16* gB = B + (size_t)(n0 + rB) * 256 + cs;
  char* dA = smc + t * 16;
  char* dB = smc + 32768 + (t >> 8) * 4096 + t * 16;

  // chunks: AE = per-wave m-half0 rows {0-63,128-191}, AO = {64-127,192-255}
  //         BE = n rows {0-31,64-95,128-159,192-223},  BO = the others
#define STAGE_AE(KT) { async16(gA + (KT), dA);                 async16(gA + 32768 + (KT), dA + 16384); }
#define STAGE_AO(KT) { async16(gA + 16384 + (KT), dA + 8192);  async16(gA + 49152 + (KT), dA + 24576); }
#define STAGE_BE(KT) { async16(gB + (KT), dB);                 async16(gB + 32768 + (KT), dB + 16384); }
#define STAGE_BO(KT) { async16(gB + 8192 + (KT), dB + 4096);   async16(gB + 40960 + (KT), dB + 20480); }

  // ---- ds_read fragment base addrs (swizzled) ----
  const int rbA = (wm * 128 + (l & 15)) * 128;
  const int rbB = 32768 + (wn * 64 + (l & 15)) * 128;
  const int sw0 = (j4 ^ (l & 7)) * 16;
  const int sw1 = ((4 + j4) ^ (l & 7)) * 16;
  const char* pA0 = smc + rbA + sw0;
  const char* pA1 = smc + rbA + sw1;
  const char* pB0 = smc + rbB + sw0;
  const char* pB1 = smc + rbB + sw1;

  bf16x8 aE[4][2], aO[4][2], bE[2][2], bO[2][2];
  floatx4 acc[8][4];
  #pragma unroll
  for (int i = 0; i < 8; ++i)
    #pragma unroll
    for (int j = 0; j < 4; ++j)
      acc[i][j] = floatx4{0.f, 0.f, 0.f, 0.f};

#define MFMA_QUAD(av, bv, mo, no)                                         \
  _Pragma("unroll")                                                       \
  for (int kk = 0; kk < 2; ++kk)                                          \
    _Pragma("unroll")                                                     \
    for (int mi = 0; mi < 4; ++mi)                                        \
      _Pragma("unroll")                                                   \
      for (int nj = 0; nj < 2; ++nj)                                      \
        acc[(mo) + mi][(no) + nj] = __builtin_amdgcn_mfma_f32_16x16x32_bf16( \
            av[mi][kk], bv[nj][kk], acc[(mo) + mi][(no) + nj], 0, 0, 0);

#define PHASE_MID()                                          \
  __builtin_amdgcn_s_barrier();                              \
  asm volatile("s_waitcnt lgkmcnt(0)" ::: "memory");         \
  __builtin_amdgcn_sched_barrier(0);                         \
  __builtin_amdgcn_s_setprio(1);

#define PHASE_TAIL()                                         \
  __builtin_amdgcn_s_setprio(0);                             \
  __builtin_amdgcn_sched_barrier(0);

  // ---- prologue: stage tile 0 (order AE,BE,BO,AO), wait oldest 4 ----
  STAGE_AE(0); STAGE_BE(0); STAGE_BO(0); STAGE_AO(0);
  asm volatile("s_waitcnt vmcnt(4)" ::: "memory");
  __builtin_amdgcn_s_barrier();

  #pragma unroll
  for (int kt = 0; kt < 4; ++kt) {
    const int ktn = (kt + 1) * 64;

    // ---- P1: (mh=0,nh=0): read AE+BE, no stage ----
    #pragma unroll
    for (int mi = 0; mi < 4; ++mi) {
      aE[mi][0] = *(const bf16x8*)(pA0 + mi * 2048);
      aE[mi][1] = *(const bf16x8*)(pA1 + mi * 2048);
    }
    #pragma unroll
    for (int nj = 0; nj < 2; ++nj) {
      bE[nj][0] = *(const bf16x8*)(pB0 + nj * 2048);
      bE[nj][1] = *(const bf16x8*)(pB1 + nj * 2048);
    }
    PHASE_MID();
    MFMA_QUAD(aE, bE, 0, 0);
    PHASE_TAIL();
    asm volatile("s_waitcnt vmcnt(2)" ::: "memory");   // BO(kt) landed
    __builtin_amdgcn_s_barrier();

    // ---- P2: (mh=0,nh=1): read BO, stage AE'+BE' ----
    #pragma unroll
    for (int nj = 0; nj < 2; ++nj) {
      bO[nj][0] = *(const bf16x8*)(pB0 + 4096 + nj * 2048);
      bO[nj][1] = *(const bf16x8*)(pB1 + 4096 + nj * 2048);
    }
    if (kt < 3) { STAGE_AE(ktn); STAGE_BE(ktn); }
    PHASE_MID();
    MFMA_QUAD(aE, bO, 0, 2);
    PHASE_TAIL();
    if (kt < 3) { asm volatile("s_waitcnt vmcnt(4)" ::: "memory"); }  // AO(kt) landed
    else        { asm volatile("s_waitcnt vmcnt(0)" ::: "memory"); }
    __builtin_amdgcn_s_barrier();

    // ---- P3: (mh=1,nh=0): read AO, stage BO' ----
    #pragma unroll
    for (int mi = 0; mi < 4; ++mi) {
      aO[mi][0] = *(const bf16x8*)(pA0 + 8192 + mi * 2048);
      aO[mi][1] = *(const bf16x8*)(pA1 + 8192 + mi * 2048);
    }
    if (kt < 3) STAGE_BO(ktn);
    PHASE_MID();
    MFMA_QUAD(aO, bE, 4, 0);
    PHASE_TAIL();
    __builtin_amdgcn_s_barrier();

    // ---- P4: (mh=1,nh=1): no reads, stage AO' ----
    if (kt < 3) STAGE_AO(ktn);
    PHASE_MID();
    MFMA_QUAD(aO, bO, 4, 2);
    PHASE_TAIL();
    if (kt < 3) {
      asm volatile("s_waitcnt vmcnt(4)" ::: "memory");  // AE',BE' landed
      __builtin_amdgcn_s_barrier();
    }
  }

  // ---- epilogue: silu(g)*u -> fp8 into LDS [256][128], then coalesced stores ----
  __syncthreads();
  unsigned char* sH = (unsigned char*)smc;   // 32 KB, aliases A region
  #pragma unroll
  for (int mi = 0; mi < 8; ++mi)
    #pragma unroll
    for (int nj = 0; nj < 2; ++nj) {
      floatx4 gv4 = acc[mi][nj], uv4 = acc[mi][nj + 2];
      int fcol = wn * 32 + nj * 16 + (l & 15);
      #pragma unroll
      for (int r = 0; r < 4; ++r) {
        int mloc = wm * 128 + mi * 16 + j4 * 4 + r;
        float gvv = gv4[r], uvv = uv4[r];
        float hv = (gvv / (1.f + __expf(-gvv))) * uvv;
        sH[mloc * 128 + fcol] = to_fp8(16.f * hv);
      }
    }
  __syncthreads();
  const size_t hbase = (size_t)m0 * 1024 + (n0 >> 1);
  #pragma unroll
  for (int c = 0; c < 4; ++c) {
    int chunk = c * 512 + t;          // 2048 chunks of 16 B
    int mloc = chunk >> 3, col = chunk & 7;
    *(int4*)&H[hbase + (size_t)mloc * 1024 + col * 16] =
        *(const int4*)&sH[mloc * 128 + col * 16];
  }
#undef STAGE_AE
#undef STAGE_AO
#undef STAGE_BE
#undef STAGE_BO
#undef MFMA_QUAD
#undef PHASE_MID
#undef PHASE_TAIL
}

// ---- Kernel D: fp8 down GEMM + residual. tile 128m x 256n, BK=64 ----
__global__ __launch_bounds__(256, 2) void gemm_down(
    const unsigned char* __restrict__ A,   // h fp8 [65536][1024]
    const unsigned char* __restrict__ B,   // Wd^T fp8 [256][1024]
    const float* __restrict__ X,
    float* __restrict__ O)
{
  __shared__ unsigned char sA[128 * 64];   // 8 KB
  __shared__ unsigned char sB[256 * 64];   // 16 KB
  const int t = threadIdx.x;
  const int m0 = blockIdx.x * 128;
  const int lane = t & 63, wv = t >> 6;
  const int wm = wv & 1, wn = wv >> 1;
  const int l15 = lane & 15, quad = lane >> 4;

  int aoff[2], boff[4];
  #pragma unroll
  for (int i = 0; i < 2; ++i) {
    int idx = i * 256 + t, row = idx >> 2, q = idx & 3;
    aoff[i] = (m0 + row) * 1024 + (q ^ ((row >> 1) & 3)) * 16;
  }
  #pragma unroll
  for (int i = 0; i < 4; ++i) {
    int idx = i * 256 + t, row = idx >> 2, q = idx & 3;
    boff[i] = row * 1024 + (q ^ ((row >> 1) & 3)) * 16;
  }

  floatx4 zero = {0.f, 0.f, 0.f, 0.f};
  floatx4 acc[4][8];
  #pragma unroll
  for (int i = 0; i < 4; ++i)
    #pragma unroll
    for (int j = 0; j < 8; ++j) acc[i][j] = zero;

  int aaddr[2][4], baddr[2][8];
  #pragma unroll
  for (int s = 0; s < 2; ++s) {
    const int u = s * 4 + quad;
    #pragma unroll
    for (int i = 0; i < 4; ++i) {
      int r = wm * 64 + i * 16 + l15;
      aaddr[s][i] = r * 64 + (((u >> 1) ^ ((r >> 1) & 3)) << 4) + (u & 1) * 8;
    }
    #pragma unroll
    for (int j = 0; j < 8; ++j) {
      int r = wn * 128 + j * 16 + l15;
      baddr[s][j] = r * 64 + (((u >> 1) ^ ((r >> 1) & 3)) << 4) + (u & 1) * 8;
    }
  }

  for (int k = 0; k < 16; ++k) {
    const int kk = k * 64;
    #pragma unroll
    for (int i = 0; i < 2; ++i) async16(A + aoff[i] + kk, &sA[(i * 256 + t) * 16]);
    #pragma unroll
    for (int i = 0; i < 4; ++i) async16(B + boff[i] + kk, &sB[(i * 256 + t) * 16]);
    __syncthreads();

    #pragma unroll
    for (int s = 0; s < 2; ++s) {
      long av[4], bv[8];
      #pragma unroll
      for (int i = 0; i < 4; ++i) av[i] = *(const long*)&sA[aaddr[s][i]];
      #pragma unroll
      for (int j = 0; j < 8; ++j) bv[j] = *(const long*)&sB[baddr[s][j]];
      #pragma unroll
      for (int i = 0; i < 4; ++i)
        #pragma unroll
        for (int j = 0; j < 8; ++j)
          acc[i][j] = __builtin_amdgcn_mfma_f32_16x16x32_fp8_fp8(av[i], bv[j], acc[i][j], 0, 0, 0);
    }
    __syncthreads();
  }

  #pragma unroll
  for (int i = 0; i < 4; ++i)
    #pragma unroll
    for (int j = 0; j < 8; ++j)
      #pragma unroll
      for (int r = 0; r < 4; ++r) {
        int m = m0 + wm * 64 + i * 16 + quad * 4 + r;
        int n = wn * 128 + j * 16 + l15;
        size_t o = (size_t)m * 256 + n;
        O[o] = X[o] + acc[i][j][r] * (1.f / 256.f);
      }
}

extern "C" void kernel_launch(void* const* d_in, const int* in_sizes, int n_in,
                              void* d_out, int out_size, void* d_ws, size_t ws_size,
                              hipStream_t stream) {
  const float* x   = (const float*)d_in[0];
  const float* iw  = (const float*)d_in[1];
  const float* gg  = (const float*)d_in[2];
  const float* lnw = (const float*)d_in[3];
  const float* lnb = (const float*)d_in[4];
  const float* Wg  = (const float*)d_in[5];
  const float* Wu  = (const float*)d_in[6];
  const float* Wd  = (const float*)d_in[7];
  float* out = (float*)d_out;

  char* ws = (char*)d_ws;
  __bf16*        flat = (__bf16*)(ws);                       // 32 MB
  unsigned char* h    = (unsigned char*)(ws + 33554432);     // 64 MB
  __bf16*        Bil  = (__bf16*)(ws + 100663296);           // 1 MB
  unsigned char* Bd   = (unsigned char*)(ws + 101711872);    // 256 KB

  transpose_cast_gu<<<dim3(32, 8), 256, 0, stream>>>(Wg, Bil, 0);
  transpose_cast_gu<<<dim3(32, 8), 256, 0, stream>>>(Wu, Bil, 1);
  transpose_cast_fp8<<<dim3(8, 32), 256, 0, stream>>>(Wd, Bd, 1024, 256);
  geo_ln<<<8192, 256, 0, stream>>>(x, iw, gg, lnw, lnb, flat);
  gemm_gateup<<<2048, 512, 0, stream>>>(flat, Bil, h);
  gemm_down<<<512, 256, 0, stream>>>(h, Bd, x, out);
}

// Round 2
// 281.486 us; speedup vs baseline: 1.0152x; 1.0007x over previous
//
#include <hip/hip_runtime.h>
#include <hip/hip_bf16.h>
#include <hip/hip_fp8.h>

typedef __bf16 bf16x8 __attribute__((ext_vector_type(8)));
typedef float floatx4 __attribute__((ext_vector_type(4)));

// ---- Cl(3) Cayley table, row i = first operand, col j = second. p = i*8+j ----
constexpr int TK[64] = {
  0,1,2,3,4,5,6,7,
  1,0,4,5,2,3,7,6,
  2,4,0,6,1,7,3,5,
  3,5,6,0,7,1,2,4,
  4,2,1,7,0,6,5,3,
  5,3,7,1,6,0,4,2,
  6,7,3,2,5,4,0,1,
  7,6,5,4,3,2,1,0
};
constexpr float SGN[64] = {
  1, 1, 1, 1, 1, 1, 1, 1,
  1, 1, 1, 1, 1, 1, 1, 1,
  1,-1, 1, 1,-1,-1, 1,-1,
  1,-1,-1, 1, 1,-1,-1, 1,
  1,-1, 1, 1,-1,-1, 1,-1,
  1,-1,-1, 1, 1,-1,-1, 1,
  1, 1,-1, 1,-1, 1,-1,-1,
  1, 1,-1, 1,-1, 1,-1,-1
};

__device__ __forceinline__ void async16(const void* g, void* l) {
  __builtin_amdgcn_global_load_lds(
      (const __attribute__((address_space(1))) void*)g,
      (__attribute__((address_space(3))) void*)l, 16, 0, 0);
}

__device__ __forceinline__ unsigned char to_fp8(float v) {
  __hip_fp8_e4m3 q(v);
  return (unsigned char)q.__x;
}

// ---- transpose+cast fp32 [K=256][N=1024] -> bf16 B_il[n][256], g/u 16-interleave ----
// dst row n = (f>>4)*32 + sel*16 + (f&15)
__global__ __launch_bounds__(256) void transpose_cast_gu(
    const float* __restrict__ src, __bf16* __restrict__ dst, int sel)
{
  __shared__ float s[32 * 33];
  const int t = threadIdx.x;
  const int k0 = blockIdx.y * 32, f0 = blockIdx.x * 32;
  const int r = t >> 5, c = t & 31;
  #pragma unroll
  for (int i = 0; i < 4; ++i)
    s[(r + i * 8) * 33 + c] = src[(size_t)(k0 + r + i * 8) * 1024 + f0 + c];
  __syncthreads();
  #pragma unroll
  for (int i = 0; i < 4; ++i) {
    int f = f0 + r + i * 8;
    int n = ((f >> 4) << 5) + sel * 16 + (f & 15);
    dst[(size_t)n * 256 + k0 + c] = (__bf16)s[c * 33 + r + i * 8];
  }
}

// ---- transpose+cast fp32 [K][N] -> fp8 [N][K], value*16 ----
__global__ __launch_bounds__(256) void transpose_cast_fp8(
    const float* __restrict__ src, unsigned char* __restrict__ dst, int K, int N)
{
  __shared__ float s[32 * 33];
  const int t = threadIdx.x;
  const int k0 = blockIdx.y * 32, n0 = blockIdx.x * 32;
  const int r = t >> 5, c = t & 31;
  #pragma unroll
  for (int i = 0; i < 4; ++i)
    s[(r + i * 8) * 33 + c] = src[(size_t)(k0 + r + i * 8) * N + n0 + c];
  __syncthreads();
  #pragma unroll
  for (int i = 0; i < 4; ++i)
    dst[(size_t)(n0 + r + i * 8) * K + k0 + c] = to_fp8(16.f * s[c * 33 + r + i * 8]);
}

// ---- geometric product + gate mix + LayerNorm -> bf16 flat [65536][256] ----
__global__ __launch_bounds__(256) void geo_ln(
    const float* __restrict__ X,   // [8192][8][256]
    const float* __restrict__ IW,  // [64]
    const float* __restrict__ GG,  // [1]
    const float* __restrict__ LW, const float* __restrict__ LB,
    __bf16* __restrict__ F)        // [65536][256]
{
  __shared__ float sw[64];
  __shared__ float smix[8 * 256];
  __shared__ float sstat[16];
  const int t = threadIdx.x;
  const int tok = blockIdx.x;

  if (t < 64) sw[t] = SGN[t] / (1.f + __expf(-IW[t]));

  float xv[8];
  #pragma unroll
  for (int b = 0; b < 8; ++b) xv[b] = X[(size_t)tok * 2048 + b * 256 + t];
  const float g = 1.f / (1.f + __expf(-GG[0]));

  __syncthreads();

  float geo[8] = {0.f, 0.f, 0.f, 0.f, 0.f, 0.f, 0.f, 0.f};
  #pragma unroll
  for (int p = 0; p < 64; ++p)
    geo[TK[p]] += xv[p >> 3] * xv[p & 7] * sw[p];

  float mv[8];
  #pragma unroll
  for (int b = 0; b < 8; ++b) {
    mv[b] = g * geo[b] + (1.f - g) * xv[b];
    smix[b * 256 + t] = mv[b];
  }
  __syncthreads();

  const int wv = t >> 6, lane = t & 63;
  #pragma unroll
  for (int s = 0; s < 2; ++s) {
    int b = wv * 2 + s;
    float v0 = smix[b * 256 + lane];
    float v1 = smix[b * 256 + 64 + lane];
    float v2 = smix[b * 256 + 128 + lane];
    float v3 = smix[b * 256 + 192 + lane];
    float sum = v0 + v1 + v2 + v3;
    float sq  = v0*v0 + v1*v1 + v2*v2 + v3*v3;
    #pragma unroll
    for (int off = 32; off > 0; off >>= 1) {
      sum += __shfl_xor(sum, off, 64);
      sq  += __shfl_xor(sq,  off, 64);
    }
    if (lane == 0) {
      float mu  = sum * (1.f / 256.f);
      float var = sq * (1.f / 256.f) - mu * mu;
      sstat[b]     = mu;
      sstat[8 + b] = rsqrtf(var + 1e-5f);
    }
  }
  __syncthreads();

  const float lw = LW[t], lb = LB[t];
  #pragma unroll
  for (int b = 0; b < 8; ++b) {
    float v = (mv[b] - sstat[b]) * sstat[8 + b] * lw + lb;
    F[(size_t)(tok * 8 + b) * 256 + t] = (__bf16)v;
  }
}

// ---- Kernel C: gate+up GEMM + SwiGLU -> h fp8 (x16) ----
// m201-faithful: 256m x 256n, BK=64, 8 waves (2Mx4N), 16x16x32 bf16 MFMA.
// 128KB LDS double-buffer (tile T in buf[T&1]); half-tile stage stream
// A0,B0,B1,A1 with region lifetimes {A0:P1, B0:P1, B1:P2, A1:P3};
// wave wm owns m-rows mh*128+wm*64.., wave wn owns n-rows nh*128+wn*32..;
// ONE vmcnt(6) per 4 phases (3 half-tiles in flight). T1/T2/T5 kept.
__global__ __launch_bounds__(512, 2) void gemm_gateup(
    const __bf16* __restrict__ A,   // flat [65536][256]
    const __bf16* __restrict__ B,   // B_il [2048][256]
    unsigned char* __restrict__ H)  // fp8 [65536][1024]
{
  __shared__ __align__(16) char smc[131072];

  const int t = threadIdx.x;
  const int l = t & 63;
  const int wv = t >> 6, wm = wv & 1, wn = wv >> 1;
  const int l15 = l & 15, j4 = l >> 4;

  // XCD-aware bijective swizzle: 8 n-blocks of an m-panel on one XCD
  const int bid = blockIdx.x;
  const int lid = (bid & 7) * 256 + (bid >> 3);
  const int m0 = (lid >> 3) * 256;
  const int n0 = (lid & 7) * 256;

  // ---- staging: pre-swizzled global source, linear LDS dest ----
  const int cs = ((t & 7) ^ ((t >> 3) & 7)) * 8;   // k-slot swizzle, elements
  const __bf16* gA = A + (size_t)(m0 + (t >> 3)) * 256 + cs;
  const __bf16* gB = B + (size_t)(n0 + (t >> 3)) * 256 + cs;

  // regions per buf p (64KB): A0 @0, A1 @16K, B0 @32K, B1 @48K
#define STAGE_A(p, h, kt) {                                                        \
  async16(gA + (h) * 32768 + (kt) * 64,         smc + (p) * 65536 + (h) * 16384 + t * 16);        \
  async16(gA + (h) * 32768 + 16384 + (kt) * 64, smc + (p) * 65536 + (h) * 16384 + 8192 + t * 16); }
#define STAGE_B(p, h, kt) {                                                        \
  async16(gB + (h) * 32768 + (kt) * 64,         smc + (p) * 65536 + 32768 + (h) * 16384 + t * 16);        \
  async16(gB + (h) * 32768 + 16384 + (kt) * 64, smc + (p) * 65536 + 32768 + (h) * 16384 + 8192 + t * 16); }

  // ---- ds_read fragment addressing (swizzled) ----
  const int sw0 = (j4 ^ (l15 & 7)) * 16;
  const int sw1 = ((4 + j4) ^ (l15 & 7)) * 16;
  const char* pAr = smc + (wm * 64 + l15) * 128;
  const char* pBr = smc + 32768 + (wn * 32 + l15) * 128;

  bf16x8 aF[4][2], bE[2][2], bO[2][2];
  floatx4 acc[8][4];
  #pragma unroll
  for (int i = 0; i < 8; ++i)
    #pragma unroll
    for (int j = 0; j < 4; ++j)
      acc[i][j] = floatx4{0.f, 0.f, 0.f, 0.f};

#define READ_A(mh, p)                                                              \
  _Pragma("unroll")                                                                \
  for (int mi = 0; mi < 4; ++mi) {                                                 \
    aF[mi][0] = *(const bf16x8*)(pAr + (p) * 65536 + (mh) * 16384 + mi * 2048 + sw0); \
    aF[mi][1] = *(const bf16x8*)(pAr + (p) * 65536 + (mh) * 16384 + mi * 2048 + sw1); \
  }
#define READ_B(dst, nh, p)                                                         \
  _Pragma("unroll")                                                                \
  for (int nj = 0; nj < 2; ++nj) {                                                 \
    dst[nj][0] = *(const bf16x8*)(pBr + (p) * 65536 + (nh) * 16384 + nj * 2048 + sw0); \
    dst[nj][1] = *(const bf16x8*)(pBr + (p) * 65536 + (nh) * 16384 + nj * 2048 + sw1); \
  }

#define MFMA16(av, bv, mo, no)                                            \
  _Pragma("unroll")                                                       \
  for (int kk = 0; kk < 2; ++kk)                                          \
    _Pragma("unroll")                                                     \
    for (int mi = 0; mi < 4; ++mi)                                        \
      _Pragma("unroll")                                                   \
      for (int nj = 0; nj < 2; ++nj)                                      \
        acc[(mo) + mi][(no) + nj] = __builtin_amdgcn_mfma_f32_16x16x32_bf16( \
            av[mi][kk], bv[nj][kk], acc[(mo) + mi][(no) + nj], 0, 0, 0);

#define DO_MFMA(av, bv, mo, no)                              \
  __builtin_amdgcn_s_barrier();                              \
  asm volatile("s_waitcnt lgkmcnt(0)" ::: "memory");         \
  __builtin_amdgcn_sched_barrier(0);                         \
  __builtin_amdgcn_s_setprio(1);                             \
  MFMA16(av, bv, mo, no);                                    \
  __builtin_amdgcn_s_setprio(0);                             \
  __builtin_amdgcn_sched_barrier(0);

  // ---- prologue: tile0 {A0,B0,B1,A1}, tile1 {A0,B0,B1} = 14 loads ----
  STAGE_A(0, 0, 0); STAGE_B(0, 0, 0); STAGE_B(0, 1, 0); STAGE_A(0, 1, 0);
  STAGE_A(1, 0, 1); STAGE_B(1, 0, 1); STAGE_B(1, 1, 1);
  asm volatile("s_waitcnt vmcnt(6)" ::: "memory");   // tile0 fully landed
  __builtin_amdgcn_s_barrier();

  #pragma unroll
  for (int T = 0; T < 4; ++T) {
    const int p = T & 1, q = p ^ 1;

    // ---- P1: read A(mh=0)+B(nh=0) [12 ds]; stage A1(T+1) ----
    READ_A(0, p);
    READ_B(bE, 0, p);
    if (T + 1 < 4) STAGE_A(q, 1, T + 1);
    asm volatile("s_waitcnt lgkmcnt(8)" ::: "memory");
    DO_MFMA(aF, bE, 0, 0);
    __builtin_amdgcn_s_barrier();

    // ---- P2: read B(nh=1); stage A0(T+2) ----
    READ_B(bO, 1, p);
    if (T + 2 < 4) STAGE_A(p, 0, T + 2);
    DO_MFMA(aF, bO, 0, 2);
    __builtin_amdgcn_s_barrier();

    // ---- P3: read A(mh=1); stage B0(T+2) ----
    READ_A(1, p);
    if (T + 2 < 4) STAGE_B(p, 0, T + 2);
    DO_MFMA(aF, bO, 4, 2);
    __builtin_amdgcn_s_barrier();

    // ---- P4: no reads; stage B1(T+2); counted vmcnt ----
    if (T + 2 < 4) STAGE_B(p, 1, T + 2);
    DO_MFMA(aF, bE, 4, 0);
    if (T < 2)       { asm volatile("s_waitcnt vmcnt(6)" ::: "memory"); }
    else if (T == 2) { asm volatile("s_waitcnt vmcnt(0)" ::: "memory"); }
    __builtin_amdgcn_s_barrier();
  }

  // ---- epilogue: silu(g)*u -> fp8 into LDS [256][128], coalesced stores ----
  __syncthreads();
  unsigned char* sH = (unsigned char*)smc;
  #pragma unroll
  for (int mi8 = 0; mi8 < 8; ++mi8) {
    const int mh = mi8 >> 2, mi = mi8 & 3;
    #pragma unroll
    for (int nh = 0; nh < 2; ++nh) {
      floatx4 gv4 = acc[mi8][nh * 2], uv4 = acc[mi8][nh * 2 + 1];
      int fcol = (nh * 4 + wn) * 16 + l15;
      #pragma unroll
      for (int r = 0; r < 4; ++r) {
        int mloc = mh * 128 + wm * 64 + mi * 16 + j4 * 4 + r;
        float gvv = gv4[r], uvv = uv4[r];
        float hv = (gvv / (1.f + __expf(-gvv))) * uvv;
        sH[mloc * 128 + fcol] = to_fp8(16.f * hv);
      }
    }
  }
  __syncthreads();
  const size_t hbase = (size_t)m0 * 1024 + (n0 >> 1);
  #pragma unroll
  for (int c = 0; c < 4; ++c) {
    int chunk = c * 512 + t;          // 2048 chunks of 16 B
    int mloc = chunk >> 3, col = chunk & 7;
    *(int4*)&H[hbase + (size_t)mloc * 1024 + col * 16] =
        *(const int4*)&sH[mloc * 128 + col * 16];
  }
#undef STAGE_A
#undef STAGE_B
#undef READ_A
#undef READ_B
#undef MFMA16
#undef DO_MFMA
}

// ---- Kernel D: fp8 down GEMM + residual. tile 128m x 256n, BK=64 ----
__global__ __launch_bounds__(256, 2) void gemm_down(
    const unsigned char* __restrict__ A,   // h fp8 [65536][1024]
    const unsigned char* __restrict__ B,   // Wd^T fp8 [256][1024]
    const float* __restrict__ X,
    float* __restrict__ O)
{
  __shared__ unsigned char sA[128 * 64];   // 8 KB
  __shared__ unsigned char sB[256 * 64];   // 16 KB
  const int t = threadIdx.x;
  const int m0 = blockIdx.x * 128;
  const int lane = t & 63, wv = t >> 6;
  const int wm = wv & 1, wn = wv >> 1;
  const int l15 = lane & 15, quad = lane >> 4;

  int aoff[2], boff[4];
  #pragma unroll
  for (int i = 0; i < 2; ++i) {
    int idx = i * 256 + t, row = idx >> 2, q = idx & 3;
    aoff[i] = (m0 + row) * 1024 + (q ^ ((row >> 1) & 3)) * 16;
  }
  #pragma unroll
  for (int i = 0; i < 4; ++i) {
    int idx = i * 256 + t, row = idx >> 2, q = idx & 3;
    boff[i] = row * 1024 + (q ^ ((row >> 1) & 3)) * 16;
  }

  floatx4 zero = {0.f, 0.f, 0.f, 0.f};
  floatx4 acc[4][8];
  #pragma unroll
  for (int i = 0; i < 4; ++i)
    #pragma unroll
    for (int j = 0; j < 8; ++j) acc[i][j] = zero;

  int aaddr[2][4], baddr[2][8];
  #pragma unroll
  for (int s = 0; s < 2; ++s) {
    const int u = s * 4 + quad;
    #pragma unroll
    for (int i = 0; i < 4; ++i) {
      int r = wm * 64 + i * 16 + l15;
      aaddr[s][i] = r * 64 + (((u >> 1) ^ ((r >> 1) & 3)) << 4) + (u & 1) * 8;
    }
    #pragma unroll
    for (int j = 0; j < 8; ++j) {
      int r = wn * 128 + j * 16 + l15;
      baddr[s][j] = r * 64 + (((u >> 1) ^ ((r >> 1) & 3)) << 4) + (u & 1) * 8;
    }
  }

  for (int k = 0; k < 16; ++k) {
    const int kk = k * 64;
    #pragma unroll
    for (int i = 0; i < 2; ++i) async16(A + aoff[i] + kk, &sA[(i * 256 + t) * 16]);
    #pragma unroll
    for (int i = 0; i < 4; ++i) async16(B + boff[i] + kk, &sB[(i * 256 + t) * 16]);
    __syncthreads();

    #pragma unroll
    for (int s = 0; s < 2; ++s) {
      long av[4], bv[8];
      #pragma unroll
      for (int i = 0; i < 4; ++i) av[i] = *(const long*)&sA[aaddr[s][i]];
      #pragma unroll
      for (int j = 0; j < 8; ++j) bv[j] = *(const long*)&sB[baddr[s][j]];
      #pragma unroll
      for (int i = 0; i < 4; ++i)
        #pragma unroll
        for (int j = 0; j < 8; ++j)
          acc[i][j] = __builtin_amdgcn_mfma_f32_16x16x32_fp8_fp8(av[i], bv[j], acc[i][j], 0, 0, 0);
    }
    __syncthreads();
  }

  #pragma unroll
  for (int i = 0; i < 4; ++i)
    #pragma unroll
    for (int j = 0; j < 8; ++j)
      #pragma unroll
      for (int r = 0; r < 4; ++r) {
        int m = m0 + wm * 64 + i * 16 + quad * 4 + r;
        int n = wn * 128 + j * 16 + l15;
        size_t o = (size_t)m * 256 + n;
        O[o] = X[o] + acc[i][j][r] * (1.f / 256.f);
      }
}

extern "C" void kernel_launch(void* const* d_in, const int* in_sizes, int n_in,
                              void* d_out, int out_size, void* d_ws, size_t ws_size,
                              hipStream_t stream) {
  const float* x   = (const float*)d_in[0];
  const float* iw  = (const float*)d_in[1];
  const float* gg  = (const float*)d_in[2];
  const float* lnw = (const float*)d_in[3];
  const float* lnb = (const float*)d_in[4];
  const float* Wg  = (const float*)d_in[5];
  const float* Wu  = (const float*)d_in[6];
  const float* Wd  = (const float*)d_in[7];
  float* out = (float*)d_out;

  char* ws = (char*)d_ws;
  __bf16*        flat = (__bf16*)(ws);                       // 32 MB
  unsigned char* h    = (unsigned char*)(ws + 33554432);     // 64 MB
  __bf16*        Bil  = (__bf16*)(ws + 100663296);           // 1 MB
  unsigned char* Bd   = (unsigned char*)(ws + 101711872);    // 256 KB

  transpose_cast_gu<<<dim3(32, 8), 256, 0, stream>>>(Wg, Bil, 0);
  transpose_cast_gu<<<dim3(32, 8), 256, 0, stream>>>(Wu, Bil, 1);
  transpose_cast_fp8<<<dim3(8, 32), 256, 0, stream>>>(Wd, Bd, 1024, 256);
  geo_ln<<<8192, 256, 0, stream>>>(x, iw, gg, lnw, lnb, flat);
  gemm_gateup<<<2048, 512, 0, stream>>>(flat, Bil, h);
  gemm_down<<<512, 256, 0, stream>>>(h, Bd, x, out);
}

// Round 3
// 275.161 us; speedup vs baseline: 1.0386x; 1.0230x over previous
//
#include <hip/hip_runtime.h>
#include <hip/hip_bf16.h>
#include <hip/hip_fp8.h>

typedef __bf16 bf16x8 __attribute__((ext_vector_type(8)));
typedef float floatx4 __attribute__((ext_vector_type(4)));

// ---- Cl(3) Cayley table, row i = first operand, col j = second. p = i*8+j ----
constexpr int TK[64] = {
  0,1,2,3,4,5,6,7,
  1,0,4,5,2,3,7,6,
  2,4,0,6,1,7,3,5,
  3,5,6,0,7,1,2,4,
  4,2,1,7,0,6,5,3,
  5,3,7,1,6,0,4,2,
  6,7,3,2,5,4,0,1,
  7,6,5,4,3,2,1,0
};
constexpr float SGN[64] = {
  1, 1, 1, 1, 1, 1, 1, 1,
  1, 1, 1, 1, 1, 1, 1, 1,
  1,-1, 1, 1,-1,-1, 1,-1,
  1,-1,-1, 1, 1,-1,-1, 1,
  1,-1, 1, 1,-1,-1, 1,-1,
  1,-1,-1, 1, 1,-1,-1, 1,
  1, 1,-1, 1,-1, 1,-1,-1,
  1, 1,-1, 1,-1, 1,-1,-1
};

__device__ __forceinline__ void async16(const void* g, void* l) {
  __builtin_amdgcn_global_load_lds(
      (const __attribute__((address_space(1))) void*)g,
      (__attribute__((address_space(3))) void*)l, 16, 0, 0);
}

__device__ __forceinline__ unsigned char to_fp8(float v) {
  __hip_fp8_e4m3 q(v);
  return (unsigned char)q.__x;
}

// ---- transpose+cast fp32 [K=256][N=1024] -> bf16 B_il[n][256], g/u 16-interleave ----
// dst row n = (f>>4)*32 + sel*16 + (f&15)
__global__ __launch_bounds__(256) void transpose_cast_gu(
    const float* __restrict__ src, __bf16* __restrict__ dst, int sel)
{
  __shared__ float s[32 * 33];
  const int t = threadIdx.x;
  const int k0 = blockIdx.y * 32, f0 = blockIdx.x * 32;
  const int r = t >> 5, c = t & 31;
  #pragma unroll
  for (int i = 0; i < 4; ++i)
    s[(r + i * 8) * 33 + c] = src[(size_t)(k0 + r + i * 8) * 1024 + f0 + c];
  __syncthreads();
  #pragma unroll
  for (int i = 0; i < 4; ++i) {
    int f = f0 + r + i * 8;
    int n = ((f >> 4) << 5) + sel * 16 + (f & 15);
    dst[(size_t)n * 256 + k0 + c] = (__bf16)s[c * 33 + r + i * 8];
  }
}

// ---- transpose+cast fp32 [K][N] -> fp8 [N][K], value*16 ----
__global__ __launch_bounds__(256) void transpose_cast_fp8(
    const float* __restrict__ src, unsigned char* __restrict__ dst, int K, int N)
{
  __shared__ float s[32 * 33];
  const int t = threadIdx.x;
  const int k0 = blockIdx.y * 32, n0 = blockIdx.x * 32;
  const int r = t >> 5, c = t & 31;
  #pragma unroll
  for (int i = 0; i < 4; ++i)
    s[(r + i * 8) * 33 + c] = src[(size_t)(k0 + r + i * 8) * N + n0 + c];
  __syncthreads();
  #pragma unroll
  for (int i = 0; i < 4; ++i)
    dst[(size_t)(n0 + r + i * 8) * K + k0 + c] = to_fp8(16.f * s[c * 33 + r + i * 8]);
}

// ---- geometric product + gate mix + LayerNorm -> bf16 flat [65536][256] ----
__global__ __launch_bounds__(256) void geo_ln(
    const float* __restrict__ X,   // [8192][8][256]
    const float* __restrict__ IW,  // [64]
    const float* __restrict__ GG,  // [1]
    const float* __restrict__ LW, const float* __restrict__ LB,
    __bf16* __restrict__ F)        // [65536][256]
{
  __shared__ float sw[64];
  __shared__ float smix[8 * 256];
  __shared__ float sstat[16];
  const int t = threadIdx.x;
  const int tok = blockIdx.x;

  if (t < 64) sw[t] = SGN[t] / (1.f + __expf(-IW[t]));

  float xv[8];
  #pragma unroll
  for (int b = 0; b < 8; ++b) xv[b] = X[(size_t)tok * 2048 + b * 256 + t];
  const float g = 1.f / (1.f + __expf(-GG[0]));

  __syncthreads();

  float geo[8] = {0.f, 0.f, 0.f, 0.f, 0.f, 0.f, 0.f, 0.f};
  #pragma unroll
  for (int p = 0; p < 64; ++p)
    geo[TK[p]] += xv[p >> 3] * xv[p & 7] * sw[p];

  float mv[8];
  #pragma unroll
  for (int b = 0; b < 8; ++b) {
    mv[b] = g * geo[b] + (1.f - g) * xv[b];
    smix[b * 256 + t] = mv[b];
  }
  __syncthreads();

  const int wv = t >> 6, lane = t & 63;
  #pragma unroll
  for (int s = 0; s < 2; ++s) {
    int b = wv * 2 + s;
    float v0 = smix[b * 256 + lane];
    float v1 = smix[b * 256 + 64 + lane];
    float v2 = smix[b * 256 + 128 + lane];
    float v3 = smix[b * 256 + 192 + lane];
    float sum = v0 + v1 + v2 + v3;
    float sq  = v0*v0 + v1*v1 + v2*v2 + v3*v3;
    #pragma unroll
    for (int off = 32; off > 0; off >>= 1) {
      sum += __shfl_xor(sum, off, 64);
      sq  += __shfl_xor(sq,  off, 64);
    }
    if (lane == 0) {
      float mu  = sum * (1.f / 256.f);
      float var = sq * (1.f / 256.f) - mu * mu;
      sstat[b]     = mu;
      sstat[8 + b] = rsqrtf(var + 1e-5f);
    }
  }
  __syncthreads();

  const float lw = LW[t], lb = LB[t];
  #pragma unroll
  for (int b = 0; b < 8; ++b) {
    float v = (mv[b] - sstat[b]) * sstat[8 + b] * lw + lb;
    F[(size_t)(tok * 8 + b) * 256 + t] = (__bf16)v;
  }
}

// ---- Kernel C: gate+up GEMM + SwiGLU -> h fp8 (x16) ----
// 256m x 256n, BK=64, 8 waves (2Mx4N), 16x16x32 bf16 MFMA, OPERAND-SWAPPED
// (B-frag as MFMA A-operand) so acc = C^T: reg-quad = 4 consecutive f for one m.
// 128KB LDS double-buffer, half-tile stream A0,B0,B1,A1, ONE vmcnt(6)/K-tile.
// Epilogue: silu*up -> hw packed fp8 cvt (v_cvt_pk_fp8_f32), dword LDS writes
// (group-XOR swizzled, conflict-free), coalesced 16B global stores.
__global__ __launch_bounds__(512, 2) void gemm_gateup(
    const __bf16* __restrict__ A,   // flat [65536][256]
    const __bf16* __restrict__ B,   // B_il [2048][256]
    unsigned char* __restrict__ H)  // fp8 [65536][1024]
{
  __shared__ __align__(16) char smc[131072];

  const int t = threadIdx.x;
  const int l = t & 63;
  const int wv = t >> 6, wm = wv & 1, wn = wv >> 1;
  const int l15 = l & 15, j4 = l >> 4;

  // XCD-aware bijective swizzle: 8 n-blocks of an m-panel on one XCD
  const int bid = blockIdx.x;
  const int lid = (bid & 7) * 256 + (bid >> 3);
  const int m0 = (lid >> 3) * 256;
  const int n0 = (lid & 7) * 256;

  // ---- staging: pre-swizzled global source, linear LDS dest ----
  const int cs = ((t & 7) ^ ((t >> 3) & 7)) * 8;   // k-slot swizzle, elements
  const __bf16* gA = A + (size_t)(m0 + (t >> 3)) * 256 + cs;
  const __bf16* gB = B + (size_t)(n0 + (t >> 3)) * 256 + cs;

  // regions per buf p (64KB): A0 @0, A1 @16K, B0 @32K, B1 @48K
#define STAGE_A(p, h, kt) {                                                        \
  async16(gA + (h) * 32768 + (kt) * 64,         smc + (p) * 65536 + (h) * 16384 + t * 16);        \
  async16(gA + (h) * 32768 + 16384 + (kt) * 64, smc + (p) * 65536 + (h) * 16384 + 8192 + t * 16); }
#define STAGE_B(p, h, kt) {                                                        \
  async16(gB + (h) * 32768 + (kt) * 64,         smc + (p) * 65536 + 32768 + (h) * 16384 + t * 16);        \
  async16(gB + (h) * 32768 + 16384 + (kt) * 64, smc + (p) * 65536 + 32768 + (h) * 16384 + 8192 + t * 16); }

  // ---- ds_read fragment addressing (swizzled) ----
  const int sw0 = (j4 ^ (l15 & 7)) * 16;
  const int sw1 = ((4 + j4) ^ (l15 & 7)) * 16;
  const char* pAr = smc + (wm * 64 + l15) * 128;
  const char* pBr = smc + 32768 + (wn * 32 + l15) * 128;

  bf16x8 aF[4][2], bE[2][2], bO[2][2];
  floatx4 acc[4][8];       // [f-frag: nh*2+sel][m-frag: mh*4+mi]
  #pragma unroll
  for (int i = 0; i < 4; ++i)
    #pragma unroll
    for (int j = 0; j < 8; ++j)
      acc[i][j] = floatx4{0.f, 0.f, 0.f, 0.f};

#define READ_A(mh, p)                                                              \
  _Pragma("unroll")                                                                \
  for (int mi = 0; mi < 4; ++mi) {                                                 \
    aF[mi][0] = *(const bf16x8*)(pAr + (p) * 65536 + (mh) * 16384 + mi * 2048 + sw0); \
    aF[mi][1] = *(const bf16x8*)(pAr + (p) * 65536 + (mh) * 16384 + mi * 2048 + sw1); \
  }
#define READ_B(dst, nh, p)                                                         \
  _Pragma("unroll")                                                                \
  for (int nj = 0; nj < 2; ++nj) {                                                 \
    dst[nj][0] = *(const bf16x8*)(pBr + (p) * 65536 + (nh) * 16384 + nj * 2048 + sw0); \
    dst[nj][1] = *(const bf16x8*)(pBr + (p) * 65536 + (nh) * 16384 + nj * 2048 + sw1); \
  }

  // operand-swapped: B-frag is the MFMA A-operand -> acc = C^T[f][m]
#define MFMA16(av, bv, mo, no)                                            \
  _Pragma("unroll")                                                       \
  for (int kk = 0; kk < 2; ++kk)                                          \
    _Pragma("unroll")                                                     \
    for (int mi = 0; mi < 4; ++mi)                                        \
      _Pragma("unroll")                                                   \
      for (int nj = 0; nj < 2; ++nj)                                      \
        acc[(no) + nj][(mo) + mi] = __builtin_amdgcn_mfma_f32_16x16x32_bf16( \
            bv[nj][kk], av[mi][kk], acc[(no) + nj][(mo) + mi], 0, 0, 0);

#define DO_MFMA(av, bv, mo, no)                              \
  __builtin_amdgcn_s_barrier();                              \
  asm volatile("s_waitcnt lgkmcnt(0)" ::: "memory");         \
  __builtin_amdgcn_sched_barrier(0);                         \
  __builtin_amdgcn_s_setprio(1);                             \
  MFMA16(av, bv, mo, no);                                    \
  __builtin_amdgcn_s_setprio(0);                             \
  __builtin_amdgcn_sched_barrier(0);

  // ---- prologue: tile0 {A0,B0,B1,A1}, tile1 {A0,B0,B1} = 14 loads ----
  STAGE_A(0, 0, 0); STAGE_B(0, 0, 0); STAGE_B(0, 1, 0); STAGE_A(0, 1, 0);
  STAGE_A(1, 0, 1); STAGE_B(1, 0, 1); STAGE_B(1, 1, 1);
  asm volatile("s_waitcnt vmcnt(6)" ::: "memory");   // tile0 fully landed
  __builtin_amdgcn_s_barrier();

  #pragma unroll
  for (int T = 0; T < 4; ++T) {
    const int p = T & 1, q = p ^ 1;

    // ---- P1: read A(mh=0)+B(nh=0) [12 ds]; stage A1(T+1) ----
    READ_A(0, p);
    READ_B(bE, 0, p);
    if (T + 1 < 4) STAGE_A(q, 1, T + 1);
    asm volatile("s_waitcnt lgkmcnt(8)" ::: "memory");
    DO_MFMA(aF, bE, 0, 0);
    __builtin_amdgcn_s_barrier();

    // ---- P2: read B(nh=1); stage A0(T+2) ----
    READ_B(bO, 1, p);
    if (T + 2 < 4) STAGE_A(p, 0, T + 2);
    DO_MFMA(aF, bO, 0, 2);
    __builtin_amdgcn_s_barrier();

    // ---- P3: read A(mh=1); stage B0(T+2) ----
    READ_A(1, p);
    if (T + 2 < 4) STAGE_B(p, 0, T + 2);
    DO_MFMA(aF, bO, 4, 2);
    __builtin_amdgcn_s_barrier();

    // ---- P4: no reads; stage B1(T+2); counted vmcnt ----
    if (T + 2 < 4) STAGE_B(p, 1, T + 2);
    DO_MFMA(aF, bE, 4, 0);
    if (T < 2)       { asm volatile("s_waitcnt vmcnt(6)" ::: "memory"); }
    else if (T == 2) { asm volatile("s_waitcnt vmcnt(0)" ::: "memory"); }
    __builtin_amdgcn_s_barrier();
  }

  // ---- epilogue: silu(g)*u -> packed fp8 dwords in LDS [256][32 slots] ----
  __syncthreads();
  int* sW = (int*)smc;
  #pragma unroll
  for (int nh = 0; nh < 2; ++nh)
    #pragma unroll
    for (int mi8 = 0; mi8 < 8; ++mi8) {
      floatx4 gv4 = acc[nh * 2 + 0][mi8];   // gate (sel=0 frag)
      floatx4 uv4 = acc[nh * 2 + 1][mi8];   // up   (sel=1 frag)
      float h0 = 16.f * (gv4[0] / (1.f + __expf(-gv4[0]))) * uv4[0];
      float h1 = 16.f * (gv4[1] / (1.f + __expf(-gv4[1]))) * uv4[1];
      float h2 = 16.f * (gv4[2] / (1.f + __expf(-gv4[2]))) * uv4[2];
      float h3 = 16.f * (gv4[3] / (1.f + __expf(-gv4[3]))) * uv4[3];
      int w = __builtin_amdgcn_cvt_pk_fp8_f32(h0, h1, 0, false);
      w = __builtin_amdgcn_cvt_pk_fp8_f32(h2, h3, w, true);
      int mloc = (mi8 >> 2) * 128 + wm * 64 + (mi8 & 3) * 16 + l15;
      int grp = (nh * 4 + wn) ^ (mloc & 7);      // 16B-group swizzle
      sW[mloc * 32 + grp * 4 + j4] = w;
    }
  __syncthreads();
  const size_t hbase = (size_t)m0 * 1024 + (n0 >> 1);
  #pragma unroll
  for (int c = 0; c < 4; ++c) {
    int chunk = c * 512 + t;          // 2048 chunks of 16 B
    int mloc = chunk >> 3, col = chunk & 7;
    *(int4*)&H[hbase + (size_t)mloc * 1024 + col * 16] =
        *(const int4*)&sW[mloc * 32 + (col ^ (mloc & 7)) * 4];
  }
#undef STAGE_A
#undef STAGE_B
#undef READ_A
#undef READ_B
#undef MFMA16
#undef DO_MFMA
}

// ---- Kernel D: fp8 down GEMM + residual. tile 128m x 256n, BK=64 ----
__global__ __launch_bounds__(256, 2) void gemm_down(
    const unsigned char* __restrict__ A,   // h fp8 [65536][1024]
    const unsigned char* __restrict__ B,   // Wd^T fp8 [256][1024]
    const float* __restrict__ X,
    float* __restrict__ O)
{
  __shared__ unsigned char sA[128 * 64];   // 8 KB
  __shared__ unsigned char sB[256 * 64];   // 16 KB
  const int t = threadIdx.x;
  const int m0 = blockIdx.x * 128;
  const int lane = t & 63, wv = t >> 6;
  const int wm = wv & 1, wn = wv >> 1;
  const int l15 = lane & 15, quad = lane >> 4;

  int aoff[2], boff[4];
  #pragma unroll
  for (int i = 0; i < 2; ++i) {
    int idx = i * 256 + t, row = idx >> 2, q = idx & 3;
    aoff[i] = (m0 + row) * 1024 + (q ^ ((row >> 1) & 3)) * 16;
  }
  #pragma unroll
  for (int i = 0; i < 4; ++i) {
    int idx = i * 256 + t, row = idx >> 2, q = idx & 3;
    boff[i] = row * 1024 + (q ^ ((row >> 1) & 3)) * 16;
  }

  floatx4 zero = {0.f, 0.f, 0.f, 0.f};
  floatx4 acc[4][8];
  #pragma unroll
  for (int i = 0; i < 4; ++i)
    #pragma unroll
    for (int j = 0; j < 8; ++j) acc[i][j] = zero;

  int aaddr[2][4], baddr[2][8];
  #pragma unroll
  for (int s = 0; s < 2; ++s) {
    const int u = s * 4 + quad;
    #pragma unroll
    for (int i = 0; i < 4; ++i) {
      int r = wm * 64 + i * 16 + l15;
      aaddr[s][i] = r * 64 + (((u >> 1) ^ ((r >> 1) & 3)) << 4) + (u & 1) * 8;
    }
    #pragma unroll
    for (int j = 0; j < 8; ++j) {
      int r = wn * 128 + j * 16 + l15;
      baddr[s][j] = r * 64 + (((u >> 1) ^ ((r >> 1) & 3)) << 4) + (u & 1) * 8;
    }
  }

  for (int k = 0; k < 16; ++k) {
    const int kk = k * 64;
    #pragma unroll
    for (int i = 0; i < 2; ++i) async16(A + aoff[i] + kk, &sA[(i * 256 + t) * 16]);
    #pragma unroll
    for (int i = 0; i < 4; ++i) async16(B + boff[i] + kk, &sB[(i * 256 + t) * 16]);
    __syncthreads();

    #pragma unroll
    for (int s = 0; s < 2; ++s) {
      long av[4], bv[8];
      #pragma unroll
      for (int i = 0; i < 4; ++i) av[i] = *(const long*)&sA[aaddr[s][i]];
      #pragma unroll
      for (int j = 0; j < 8; ++j) bv[j] = *(const long*)&sB[baddr[s][j]];
      #pragma unroll
      for (int i = 0; i < 4; ++i)
        #pragma unroll
        for (int j = 0; j < 8; ++j)
          acc[i][j] = __builtin_amdgcn_mfma_f32_16x16x32_fp8_fp8(av[i], bv[j], acc[i][j], 0, 0, 0);
    }
    __syncthreads();
  }

  #pragma unroll
  for (int i = 0; i < 4; ++i)
    #pragma unroll
    for (int j = 0; j < 8; ++j)
      #pragma unroll
      for (int r = 0; r < 4; ++r) {
        int m = m0 + wm * 64 + i * 16 + quad * 4 + r;
        int n = wn * 128 + j * 16 + l15;
        size_t o = (size_t)m * 256 + n;
        O[o] = X[o] + acc[i][j][r] * (1.f / 256.f);
      }
}

extern "C" void kernel_launch(void* const* d_in, const int* in_sizes, int n_in,
                              void* d_out, int out_size, void* d_ws, size_t ws_size,
                              hipStream_t stream) {
  const float* x   = (const float*)d_in[0];
  const float* iw  = (const float*)d_in[1];
  const float* gg  = (const float*)d_in[2];
  const float* lnw = (const float*)d_in[3];
  const float* lnb = (const float*)d_in[4];
  const float* Wg  = (const float*)d_in[5];
  const float* Wu  = (const float*)d_in[6];
  const float* Wd  = (const float*)d_in[7];
  float* out = (float*)d_out;

  char* ws = (char*)d_ws;
  __bf16*        flat = (__bf16*)(ws);                       // 32 MB
  unsigned char* h    = (unsigned char*)(ws + 33554432);     // 64 MB
  __bf16*        Bil  = (__bf16*)(ws + 100663296);           // 1 MB
  unsigned char* Bd   = (unsigned char*)(ws + 101711872);    // 256 KB

  transpose_cast_gu<<<dim3(32, 8), 256, 0, stream>>>(Wg, Bil, 0);
  transpose_cast_gu<<<dim3(32, 8), 256, 0, stream>>>(Wu, Bil, 1);
  transpose_cast_fp8<<<dim3(8, 32), 256, 0, stream>>>(Wd, Bd, 1024, 256);
  geo_ln<<<8192, 256, 0, stream>>>(x, iw, gg, lnw, lnb, flat);
  gemm_gateup<<<2048, 512, 0, stream>>>(flat, Bil, h);
  gemm_down<<<512, 256, 0, stream>>>(h, Bd, x, out);
}